// Round 17
// baseline (61.236 us; speedup 1.0000x reference)
//
#include <hip/hip_runtime.h>
#include <hip/hip_bf16.h>

typedef __attribute__((ext_vector_type(8))) short short8;
typedef __attribute__((ext_vector_type(4))) float f32x4;

__device__ __forceinline__ unsigned short f2bf(float f){
    union { float f; unsigned u; } uf; uf.f = f;
    unsigned u = uf.u;
    u += 0x7FFFu + ((u >> 16) & 1u);   // RNE
    return (unsigned short)(u >> 16);
}
__device__ __forceinline__ int pack2(float a, float b){
    union { float f; unsigned u; } ua, ub; ua.f = a; ub.f = b;
    unsigned x = ua.u; x += 0x7FFFu + ((x >> 16) & 1u);
    unsigned y = ub.u; y += 0x7FFFu + ((y >> 16) & 1u);
    return (int)((x >> 16) | (y & 0xFFFF0000u));
}
__device__ __forceinline__ unsigned cvtpk(float lo, float hi){
    unsigned r;
    asm("v_cvt_pk_bf16_f32 %0, %1, %2" : "=v"(r) : "v"(lo), "v"(hi));
    return r;
}
__device__ __forceinline__ float fexp2(float x){
    return __builtin_amdgcn_exp2f(x);   // v_exp_f32: 2^x
}

#define N_SPATIAL 1600
#define QSCALE_LOG2E 0.25506601f   /* 32^-0.5 * log2(e), folded into q */
#define LSTR 40                    /* padded LDS row stride (u16) for GEMM tiles */

// ---------------- K1: pev (800 blocks) -> v_mf frag order + x_t transpose slab ----------------
__global__ __launch_bounds__(256) void k_head2(const float* __restrict__ x,
                                               const float* __restrict__ pw,
                                               const float* __restrict__ pg,
                                               const float* __restrict__ pb,
                                               const float* __restrict__ pm,
                                               const float* __restrict__ pv,
                                               unsigned short* __restrict__ x_t,
                                               unsigned short* __restrict__ v_mf){
    __shared__ float xs[32][163];
    int pbi = blockIdx.x;             // 800 = b*200 + h*25 + kt
    int b = pbi/200, h=(pbi/25)%8, kt=pbi%25;
    int t = threadIdx.x;
    int winStart = kt*64 - 48;
    const float* xbase = x + ((size_t)(b*256 + h*32))*N_SPATIAL;
    #pragma unroll
    for (int i=0;i<20;i++){
        int idx = t + i*256;
        int row = idx / 160, col = idx - row*160;
        int n = winStart + col;
        float val = ((unsigned)n < 1600u) ? xbase[(size_t)row*N_SPATIAL + n] : 0.f;
        xs[row][col] = val;
    }
    __syncthreads();

    {
        unsigned short* xtb = x_t + ((size_t)b*N_SPATIAL + kt*64)*256 + h*32;
        #pragma unroll
        for (int i=0;i<8;i++){
            int idx = t + i*256;          // 2048 = 64n x 32c
            int cl = idx & 31, nl = idx >> 5;
            xtb[(size_t)nl*256 + cl] = f2bf(xs[cl][nl + 48]);
        }
    }

    int f = t>>6, lane = t&63, ql = lane&15, lg = lane>>4;
    int d = (f>>1)*16 + ql;
    int c = h*32 + d;
    float inv = pg[c]*rsqrtf(pv[c]+1e-5f);
    float bias = pb[c]-pm[c]*inv;
    const float* w9 = pw + c*9;
    float w00=w9[0],w01=w9[1],w02=w9[2],w10=w9[3],w11=w9[4],w12=w9[5],w20=w9[6],w21=w9[7],w22=w9[8];
    const float* xr = xs[d];
    union { unsigned short u[8]; int4 i4; } vals;
    #pragma unroll
    for (int j=0;j<8;j++){
        int key = (f&1)*32 + (j>>2)*16 + 4*lg + (j&3);
        int n = kt*64 + key;
        int hh = n/40, ww = n - hh*40;
        int col = key + 48;
        float acc = 0.f;
        if (hh > 0){
            if (ww > 0)  acc += xr[col-41]*w00;
                         acc += xr[col-40]*w01;
            if (ww < 39) acc += xr[col-39]*w02;
        }
        if (ww > 0)  acc += xr[col-1]*w10;
                     acc += xr[col]*w11;
        if (ww < 39) acc += xr[col+1]*w12;
        if (hh < 39){
            if (ww > 0)  acc += xr[col+39]*w20;
                         acc += xr[col+40]*w21;
            if (ww < 39) acc += xr[col+41]*w22;
        }
        float out = xr[col] + acc*inv + bias;
        vals.u[j] = f2bf(out);
    }
    *reinterpret_cast<int4*>(v_mf + ((size_t)(pbi*4 + f)*64 + lane)*8) = vals.i4;
}

// ---------------- K2: qkv GEMM (r13 exact) -> qk_t[b][grp16][n][32]; q pre-scaled ----------------
__global__ __launch_bounds__(256) void k_qkv2(const unsigned short* __restrict__ x_t,
                                              const float* __restrict__ wq,
                                              const float* __restrict__ g,
                                              const float* __restrict__ be,
                                              const float* __restrict__ mu,
                                              const float* __restrict__ va,
                                              unsigned short* __restrict__ qk_t){
    __shared__ alignas(16) unsigned short a_lds[64*LSTR];
    __shared__ alignas(16) unsigned short b_lds[64*LSTR];
    int bi = blockIdx.x;                      // 4*8*25
    int b = bi / 200, ot = (bi/25) % 8, nt = bi % 25;
    int o0 = ot*64, n0 = nt*64;
    int tid = threadIdx.x, w = tid>>6, lane = tid&63;
    int row = tid>>2, col8 = (tid&3)*8;
    int ql = lane&15, lg = lane>>4;
    f32x4 acc[4];
    #pragma unroll
    for (int t=0;t<4;t++) acc[t] = (f32x4){0.f,0.f,0.f,0.f};
    const float* asrc = wq + (size_t)(o0+row)*256 + col8;
    const unsigned short* bsrc = x_t + ((size_t)b*N_SPATIAL + n0 + row)*256 + col8;
    for (int k0=0; k0<256; k0+=32){
        float4 f0 = *reinterpret_cast<const float4*>(asrc + k0);
        float4 f1 = *reinterpret_cast<const float4*>(asrc + k0 + 4);
        int4 av; av.x = pack2(f0.x,f0.y); av.y = pack2(f0.z,f0.w);
                 av.z = pack2(f1.x,f1.y); av.w = pack2(f1.z,f1.w);
        *reinterpret_cast<int4*>(&a_lds[row*LSTR + col8]) = av;
        *reinterpret_cast<int4*>(&b_lds[row*LSTR + col8]) = *reinterpret_cast<const int4*>(bsrc + k0);
        __syncthreads();
        short8 af = *reinterpret_cast<const short8*>(&a_lds[(16*w + ql)*LSTR + lg*8]);
        #pragma unroll
        for (int t=0;t<4;t++){
            short8 bf = *reinterpret_cast<const short8*>(&b_lds[(16*t + ql)*LSTR + lg*8]);
            acc[t] = __builtin_amdgcn_mfma_f32_16x16x32_bf16(af, bf, acc[t], 0, 0, 0);
        }
        __syncthreads();
    }
    int ob = o0 + 16*w + 4*lg;
    int grp = ob >> 5, d0 = ob & 31;
    float invr[4], b2r[4];
    #pragma unroll
    for (int r=0;r<4;r++){
        int o = ob + r;
        invr[r] = g[o] * rsqrtf(va[o] + 1e-5f);
        b2r[r]  = be[o] - mu[o]*invr[r];
    }
    float qs = (ob < 256) ? QSCALE_LOG2E : 1.0f;
    unsigned short* dstb = qk_t + ((size_t)(b*16 + grp)*N_SPATIAL)*32 + d0;
    #pragma unroll
    for (int t=0;t<4;t++){
        int n = n0 + 16*t + ql;
        float y[4];
        #pragma unroll
        for (int r=0;r<4;r++){
            float z = acc[t][r]*invr[r] + b2r[r];
            y[r] = (z / (1.f + __expf(-z))) * qs;
        }
        uint2 wv = make_uint2((unsigned)pack2(y[0],y[1]), (unsigned)pack2(y[2],y[3]));
        *reinterpret_cast<uint2*>(dstb + (size_t)n*32) = wv;
    }
}

// ---------------- K3: attention v9 — paired K-tiles, 13 barrier intervals, setprio ----------------
__global__ __launch_bounds__(512) void k_attn9(const unsigned short* __restrict__ qk_t,
                                               const unsigned short* __restrict__ v_mf,
                                               unsigned short* __restrict__ ao_t){
    __shared__ alignas(16) unsigned short k_lds[2][2*2560];   // [pair-buf][tile][64*40]
    __shared__ alignas(16) unsigned short v_lds[2][2*2048];   // [pair-buf][tile][frag-order]
    int l = blockIdx.x;
    int xc = l & 7, j = l >> 3;
    int gg = xc + 8*(j/25);
    int b = gg >> 3, h = gg & 7, qt = j % 25;
    int tid = threadIdx.x, w = tid>>6, lane = tid&63;

    const unsigned short* ksrc = qk_t + ((size_t)(b*16+8+h)*N_SPATIAL)*32;
    const unsigned short* vms  = v_mf + (size_t)(b*200 + h*25)*2048;

    if (w < 4){
        // ---------------- consumer ----------------
        int ql = lane&15, lg = lane>>4;
        int nq = qt*64 + w*16 + ql;
        const unsigned short* qsrc = qk_t + ((size_t)(b*16+h)*N_SPATIAL)*32;
        short8 qf = *reinterpret_cast<const short8*>(qsrc + (size_t)nq*32 + lg*8);
        f32x4 o0 = (f32x4){0.f,0.f,0.f,0.f};
        f32x4 o1 = (f32x4){0.f,0.f,0.f,0.f};
        float Sp = 0.f;

        asm volatile("" ::: "memory");
        __builtin_amdgcn_s_barrier();            // prologue
        asm volatile("" ::: "memory");

        for (int iv = 0; iv < 13; ++iv){
            bool pair2 = (iv < 12);
            const unsigned short* kb = &k_lds[iv&1][0];
            const unsigned short* vb = &v_lds[iv&1][0];

            __builtin_amdgcn_s_setprio(1);
            // K frags, both tiles up-front (latency overlap)
            short8 a0 = *reinterpret_cast<const short8*>(kb + (size_t)( 0 + ql)*40 + lg*8);
            short8 a1 = *reinterpret_cast<const short8*>(kb + (size_t)(16 + ql)*40 + lg*8);
            short8 a2 = *reinterpret_cast<const short8*>(kb + (size_t)(32 + ql)*40 + lg*8);
            short8 a3 = *reinterpret_cast<const short8*>(kb + (size_t)(48 + ql)*40 + lg*8);
            short8 c0, c1, c2, c3;
            if (pair2){
                const unsigned short* kb1 = kb + 2560;
                c0 = *reinterpret_cast<const short8*>(kb1 + (size_t)( 0 + ql)*40 + lg*8);
                c1 = *reinterpret_cast<const short8*>(kb1 + (size_t)(16 + ql)*40 + lg*8);
                c2 = *reinterpret_cast<const short8*>(kb1 + (size_t)(32 + ql)*40 + lg*8);
                c3 = *reinterpret_cast<const short8*>(kb1 + (size_t)(48 + ql)*40 + lg*8);
            }

            f32x4 z = (f32x4){0.f,0.f,0.f,0.f};
            f32x4 pA0 = __builtin_amdgcn_mfma_f32_16x16x32_bf16(a0, qf, z, 0,0,0);
            f32x4 pA1 = __builtin_amdgcn_mfma_f32_16x16x32_bf16(a1, qf, z, 0,0,0);
            f32x4 pA2 = __builtin_amdgcn_mfma_f32_16x16x32_bf16(a2, qf, z, 0,0,0);
            f32x4 pA3 = __builtin_amdgcn_mfma_f32_16x16x32_bf16(a3, qf, z, 0,0,0);
            f32x4 pB0, pB1, pB2, pB3;
            if (pair2){
                pB0 = __builtin_amdgcn_mfma_f32_16x16x32_bf16(c0, qf, z, 0,0,0);
                pB1 = __builtin_amdgcn_mfma_f32_16x16x32_bf16(c1, qf, z, 0,0,0);
                pB2 = __builtin_amdgcn_mfma_f32_16x16x32_bf16(c2, qf, z, 0,0,0);
                pB3 = __builtin_amdgcn_mfma_f32_16x16x32_bf16(c3, qf, z, 0,0,0);
            }

            #pragma unroll
            for (int r=0;r<4;r++){
                pA0[r] = fexp2(pA0[r]);
                pA1[r] = fexp2(pA1[r]);
                pA2[r] = fexp2(pA2[r]);
                pA3[r] = fexp2(pA3[r]);
            }
            Sp += ((pA0[0]+pA0[1])+(pA0[2]+pA0[3])) + ((pA1[0]+pA1[1])+(pA1[2]+pA1[3]))
                + ((pA2[0]+pA2[1])+(pA2[2]+pA2[3])) + ((pA3[0]+pA3[1])+(pA3[2]+pA3[3]));
            union { int4 i; short8 s8; } qa0, qa1;
            qa0.i = make_int4((int)cvtpk(pA0[0],pA0[1]), (int)cvtpk(pA0[2],pA0[3]),
                              (int)cvtpk(pA1[0],pA1[1]), (int)cvtpk(pA1[2],pA1[3]));
            qa1.i = make_int4((int)cvtpk(pA2[0],pA2[1]), (int)cvtpk(pA2[2],pA2[3]),
                              (int)cvtpk(pA3[0],pA3[1]), (int)cvtpk(pA3[2],pA3[3]));
            {
                short8 v0 = *reinterpret_cast<const short8*>(vb +    0 + lane*8);
                short8 v1 = *reinterpret_cast<const short8*>(vb +  512 + lane*8);
                short8 v2 = *reinterpret_cast<const short8*>(vb + 1024 + lane*8);
                short8 v3 = *reinterpret_cast<const short8*>(vb + 1536 + lane*8);
                o0 = __builtin_amdgcn_mfma_f32_16x16x32_bf16(v0, qa0.s8, o0, 0,0,0);
                o0 = __builtin_amdgcn_mfma_f32_16x16x32_bf16(v1, qa1.s8, o0, 0,0,0);
                o1 = __builtin_amdgcn_mfma_f32_16x16x32_bf16(v2, qa0.s8, o1, 0,0,0);
                o1 = __builtin_amdgcn_mfma_f32_16x16x32_bf16(v3, qa1.s8, o1, 0,0,0);
            }
            if (pair2){
                #pragma unroll
                for (int r=0;r<4;r++){
                    pB0[r] = fexp2(pB0[r]);
                    pB1[r] = fexp2(pB1[r]);
                    pB2[r] = fexp2(pB2[r]);
                    pB3[r] = fexp2(pB3[r]);
                }
                Sp += ((pB0[0]+pB0[1])+(pB0[2]+pB0[3])) + ((pB1[0]+pB1[1])+(pB1[2]+pB1[3]))
                    + ((pB2[0]+pB2[1])+(pB2[2]+pB2[3])) + ((pB3[0]+pB3[1])+(pB3[2]+pB3[3]));
                union { int4 i; short8 s8; } qb0, qb1;
                qb0.i = make_int4((int)cvtpk(pB0[0],pB0[1]), (int)cvtpk(pB0[2],pB0[3]),
                                  (int)cvtpk(pB1[0],pB1[1]), (int)cvtpk(pB1[2],pB1[3]));
                qb1.i = make_int4((int)cvtpk(pB2[0],pB2[1]), (int)cvtpk(pB2[2],pB2[3]),
                                  (int)cvtpk(pB3[0],pB3[1]), (int)cvtpk(pB3[2],pB3[3]));
                const unsigned short* vb1 = vb + 2048;
                short8 v0 = *reinterpret_cast<const short8*>(vb1 +    0 + lane*8);
                short8 v1 = *reinterpret_cast<const short8*>(vb1 +  512 + lane*8);
                short8 v2 = *reinterpret_cast<const short8*>(vb1 + 1024 + lane*8);
                short8 v3 = *reinterpret_cast<const short8*>(vb1 + 1536 + lane*8);
                o0 = __builtin_amdgcn_mfma_f32_16x16x32_bf16(v0, qb0.s8, o0, 0,0,0);
                o0 = __builtin_amdgcn_mfma_f32_16x16x32_bf16(v1, qb1.s8, o0, 0,0,0);
                o1 = __builtin_amdgcn_mfma_f32_16x16x32_bf16(v2, qb0.s8, o1, 0,0,0);
                o1 = __builtin_amdgcn_mfma_f32_16x16x32_bf16(v3, qb1.s8, o1, 0,0,0);
            }
            __builtin_amdgcn_s_setprio(0);

            asm volatile("" ::: "memory");
            __builtin_amdgcn_s_barrier();
            asm volatile("" ::: "memory");
        }

        Sp += __shfl_xor(Sp, 16);
        Sp += __shfl_xor(Sp, 32);
        float inv = 1.f / Sp;
        size_t rowoff = ((size_t)b*N_SPATIAL + nq)*256 + h*32;
        uint2 w0 = make_uint2((unsigned)pack2(o0[0]*inv, o0[1]*inv),
                              (unsigned)pack2(o0[2]*inv, o0[3]*inv));
        *reinterpret_cast<uint2*>(ao_t + rowoff + 4*lg) = w0;
        uint2 w1 = make_uint2((unsigned)pack2(o1[0]*inv, o1[1]*inv),
                              (unsigned)pack2(o1[2]*inv, o1[3]*inv));
        *reinterpret_cast<uint2*>(ao_t + rowoff + 16 + 4*lg) = w1;
    } else {
        // ---------------- producer: stage K/V tile-pairs ----------------
        int pi = tid & 255;
        const unsigned short* kg = ksrc + pi*8;
        const unsigned short* vg = vms  + pi*8;
        unsigned short* kd = &k_lds[0][0] + (pi>>2)*40 + (pi&3)*8;
        unsigned short* vd = &v_lds[0][0] + pi*8;

        // prologue: pair0 (tiles 0,1) -> buf0 ; pair1 (tiles 2,3) -> regs
        {
            int4 k0 = *reinterpret_cast<const int4*>(kg);
            int4 k1 = *reinterpret_cast<const int4*>(kg + 2048);
            int4 v0 = *reinterpret_cast<const int4*>(vg);
            int4 v1 = *reinterpret_cast<const int4*>(vg + 2048);
            *reinterpret_cast<int4*>(kd) = k0;
            *reinterpret_cast<int4*>(kd + 2560) = k1;
            *reinterpret_cast<int4*>(vd) = v0;
            *reinterpret_cast<int4*>(vd + 2048) = v1;
        }
        int4 hk0 = *reinterpret_cast<const int4*>(kg + 2*2048);
        int4 hk1 = *reinterpret_cast<const int4*>(kg + 3*2048);
        int4 hv0 = *reinterpret_cast<const int4*>(vg + 2*2048);
        int4 hv1 = *reinterpret_cast<const int4*>(vg + 3*2048);
        asm volatile("s_waitcnt lgkmcnt(0)" ::: "memory");
        __builtin_amdgcn_s_barrier();            // prologue
        asm volatile("" ::: "memory");

        for (int iv = 0; iv < 13; ++iv){
            if (iv < 12){
                // write pair iv+1 into buf (iv+1)&1
                int wb = (iv+1)&1;
                unsigned short* kdw = kd + (size_t)wb*2*2560;
                unsigned short* vdw = vd + (size_t)wb*2*2048;
                *reinterpret_cast<int4*>(kdw) = hk0;
                *reinterpret_cast<int4*>(vdw) = hv0;
                if (2*(iv+1)+1 < 25){
                    *reinterpret_cast<int4*>(kdw + 2560) = hk1;
                    *reinterpret_cast<int4*>(vdw + 2048) = hv1;
                }
                // load pair iv+2 into regs
                if (iv+2 <= 12){
                    int t0 = 2*(iv+2);
                    hk0 = *reinterpret_cast<const int4*>(kg + (size_t)t0*2048);
                    hv0 = *reinterpret_cast<const int4*>(vg + (size_t)t0*2048);
                    if (t0+1 < 25){
                        hk1 = *reinterpret_cast<const int4*>(kg + (size_t)(t0+1)*2048);
                        hv1 = *reinterpret_cast<const int4*>(vg + (size_t)(t0+1)*2048);
                    }
                }
            }
            asm volatile("s_waitcnt lgkmcnt(0)" ::: "memory");
            __builtin_amdgcn_s_barrier();
            asm volatile("" ::: "memory");
        }
    }
}

// ---------------- K4: proj GEMM, 64o x 32n tiles (800 blocks), padded LDS ----------------
__global__ __launch_bounds__(256) void k_proj4(const unsigned short* __restrict__ ao_t,
                                               const float* __restrict__ wp,
                                               const float* __restrict__ g,
                                               const float* __restrict__ be,
                                               const float* __restrict__ mu,
                                               const float* __restrict__ va,
                                               float* __restrict__ out){
    __shared__ alignas(16) unsigned short a_lds[64*LSTR];
    __shared__ alignas(16) unsigned short b_lds[32*LSTR];
    int bi = blockIdx.x;                      // 800 = 4b * 4ot * 50nt
    int b = bi / 200, ot = (bi/50) % 4, nt = bi % 50;
    int o0 = ot*64, n0 = nt*32;
    int tid = threadIdx.x, w = tid>>6, lane = tid&63;
    int arow = tid>>2, acol8 = (tid&3)*8;
    int brow = tid>>3, bcol4 = (tid&7)*4;
    int ql = lane&15, lg = lane>>4;
    f32x4 acc[2];
    acc[0] = (f32x4){0.f,0.f,0.f,0.f};
    acc[1] = (f32x4){0.f,0.f,0.f,0.f};
    const float* asrc = wp + (size_t)(o0+arow)*256 + acol8;
    const unsigned short* bsrc = ao_t + ((size_t)b*N_SPATIAL + n0 + brow)*256 + bcol4;
    for (int k0=0; k0<256; k0+=32){
        float4 f0 = *reinterpret_cast<const float4*>(asrc + k0);
        float4 f1 = *reinterpret_cast<const float4*>(asrc + k0 + 4);
        int4 av; av.x = pack2(f0.x,f0.y); av.y = pack2(f0.z,f0.w);
                 av.z = pack2(f1.x,f1.y); av.w = pack2(f1.z,f1.w);
        *reinterpret_cast<int4*>(&a_lds[arow*LSTR + acol8]) = av;
        *reinterpret_cast<uint2*>(&b_lds[brow*LSTR + bcol4]) = *reinterpret_cast<const uint2*>(bsrc + k0);
        __syncthreads();
        short8 af = *reinterpret_cast<const short8*>(&a_lds[(16*w + ql)*LSTR + lg*8]);
        #pragma unroll
        for (int t=0;t<2;t++){
            short8 bf = *reinterpret_cast<const short8*>(&b_lds[(16*t + ql)*LSTR + lg*8]);
            acc[t] = __builtin_amdgcn_mfma_f32_16x16x32_bf16(af, bf, acc[t], 0, 0, 0);
        }
        __syncthreads();
    }
    #pragma unroll
    for (int r=0;r<4;r++){
        int o = o0 + 16*w + lg*4 + r;
        float inv = g[o] * rsqrtf(va[o] + 1e-5f);
        float b2  = be[o] - mu[o]*inv;
        float* dst = out + ((size_t)(b*256 + o))*N_SPATIAL;
        #pragma unroll
        for (int t=0;t<2;t++){
            int n = n0 + 16*t + ql;
            float z = acc[t][r]*inv + b2;
            float y = z / (1.f + __expf(-z));
            dst[n] = y;
        }
    }
}

extern "C" void kernel_launch(void* const* d_in, const int* in_sizes, int n_in,
                              void* d_out, int out_size, void* d_ws, size_t ws_size,
                              hipStream_t stream) {
    const float* x      = (const float*)d_in[0];
    const float* qkv_w  = (const float*)d_in[1];
    const float* qkv_g  = (const float*)d_in[2];
    const float* qkv_b  = (const float*)d_in[3];
    const float* qkv_m  = (const float*)d_in[4];
    const float* qkv_v  = (const float*)d_in[5];
    const float* proj_w = (const float*)d_in[6];
    const float* proj_g = (const float*)d_in[7];
    const float* proj_b = (const float*)d_in[8];
    const float* proj_m = (const float*)d_in[9];
    const float* proj_v = (const float*)d_in[10];
    const float* pe_w   = (const float*)d_in[11];
    const float* pe_g   = (const float*)d_in[12];
    const float* pe_b   = (const float*)d_in[13];
    const float* pe_m   = (const float*)d_in[14];
    const float* pe_v   = (const float*)d_in[15];

    char* ws = (char*)d_ws;
    unsigned short* x_t  = (unsigned short*)(ws);                 // 3,276,800
    unsigned short* v_mf = (unsigned short*)(ws + 3276800);       // 3,276,800
    unsigned short* qk_t = (unsigned short*)(ws + 6553600);       // 6,553,600
    unsigned short* ao_t = (unsigned short*)(ws + 13107200);      // 3,276,800
    float* outp = (float*)d_out;

    k_head2<<<800, 256, 0, stream>>>(x, pe_w, pe_g, pe_b, pe_m, pe_v, x_t, v_mf);
    k_qkv2 <<<800, 256, 0, stream>>>(x_t, qkv_w, qkv_g, qkv_b, qkv_m, qkv_v, qk_t);
    k_attn9<<<800, 512, 0, stream>>>(qk_t, v_mf, ao_t);
    k_proj4<<<800, 256, 0, stream>>>(ao_t, proj_w, proj_g, proj_b, proj_m, proj_v, outp);
}